// Round 5
// baseline (3144.447 us; speedup 1.0000x reference)
//
#include <hip/hip_runtime.h>
#include <hip/hip_bf16.h>
#include <cstdint>

#define VOCAB 32000
#define EMB   1024
#define TLEN  2048
#define NB    4
#define MTOT  (NB*TLEN)   // 8192 tokens

typedef __bf16 bf16;
typedef __bf16 bf16x8 __attribute__((ext_vector_type(8)));
typedef float  f32x4  __attribute__((ext_vector_type(4)));

// ---------------------------------------------------------------- embed ----
__global__ void embed_kernel(const int* __restrict__ idx,
                             const float* __restrict__ tok,
                             const float* __restrict__ pos,
                             bf16* __restrict__ x)
{
    int gid = blockIdx.x * 256 + threadIdx.x;
    int r   = gid >> 7;
    int c0  = (gid & 127) << 3;
    int t   = r & (TLEN - 1);
    int tk  = idx[r];
    const float4* tp = reinterpret_cast<const float4*>(tok + (long)tk * EMB + c0);
    const float4* pp = reinterpret_cast<const float4*>(pos + (long)t  * EMB + c0);
    float4 a0 = tp[0], a1 = tp[1];
    float4 b0 = pp[0], b1 = pp[1];
    bf16x8 o;
    o[0] = (bf16)(a0.x + b0.x); o[1] = (bf16)(a0.y + b0.y);
    o[2] = (bf16)(a0.z + b0.z); o[3] = (bf16)(a0.w + b0.w);
    o[4] = (bf16)(a1.x + b1.x); o[5] = (bf16)(a1.y + b1.y);
    o[6] = (bf16)(a1.z + b1.z); o[7] = (bf16)(a1.w + b1.w);
    *reinterpret_cast<bf16x8*>(x + (long)r * EMB + c0) = o;
}

// ------------------------------------------------- transpose + f32->bf16 ---
__global__ void transpose_conv_kernel(const float* __restrict__ W,
                                      bf16* __restrict__ Wt,
                                      int Kdim, int Ndim)
{
    __shared__ bf16 tile[64][65];
    int n0 = blockIdx.x * 64;
    int k0 = blockIdx.y * 64;
    int tid = threadIdx.x;
    int c  = tid & 63, r0 = tid >> 6;
#pragma unroll
    for (int i = 0; i < 16; ++i) {
        int r = r0 + i * 4;
        tile[r][c] = (bf16)W[(long)(k0 + r) * Ndim + n0 + c];
    }
    __syncthreads();
    int kc = tid & 63, nr0 = tid >> 6;
#pragma unroll
    for (int i = 0; i < 16; ++i) {
        int nr = nr0 + i * 4;
        Wt[(long)(n0 + nr) * Kdim + k0 + kc] = tile[kc][nr];
    }
}

// ------------------------------------------------------------- gll --------
__device__ __forceinline__ void gll16(const void* g, void* l)
{
    __builtin_amdgcn_global_load_lds(
        (const __attribute__((address_space(1))) unsigned int*)g,
        (__attribute__((address_space(3))) unsigned int*)l, 16, 0, 0);
}

// ------------------------------------------------- m97-style 128^2 GEMM ----
// C[M x N] = A[M x K] * Bt[N x K]^T, bf16 in, OMODE: 0 bf16 out, 1 f32 out
template<int OMODE>
__global__ __launch_bounds__(256)
void gemm_bt_kernel(const bf16* __restrict__ A, int lda, long sA,
                    const bf16* __restrict__ Bt, int ldb, long sB,
                    void* __restrict__ Cv, int ldc, long sC,
                    int K, const float* __restrict__ bias)
{
    __shared__ bf16 As[128 * 32];
    __shared__ bf16 Bs[128 * 32];

    const int tid  = threadIdx.x;
    const int lane = tid & 63;
    const int wv   = tid >> 6;
    const int wr   = wv >> 1, wc = wv & 1;
    const long zb  = blockIdx.z;

    const bf16* Ab = A  + zb * sA + (long)(blockIdx.y * 128) * lda;
    const bf16* Bb = Bt + zb * sB + (long)(blockIdx.x * 128) * ldb;

    f32x4 acc[4][4] = {};

    const int l0 = tid, l1 = tid + 256;
    const int r0s = l0 >> 2, kg0 = (l0 & 3) * 8;
    const int r1s = l1 >> 2, kg1 = (l1 & 3) * 8;

    for (int kt = 0; kt < K; kt += 32) {
        if (kt) __syncthreads();
        gll16(Ab + (long)r0s * lda + kt + kg0, &As[l0 * 8]);
        gll16(Ab + (long)r1s * lda + kt + kg1, &As[l1 * 8]);
        gll16(Bb + (long)r0s * ldb + kt + kg0, &Bs[l0 * 8]);
        gll16(Bb + (long)r1s * ldb + kt + kg1, &Bs[l1 * 8]);
        __syncthreads();

        bf16x8 af[4], bfr[4];
#pragma unroll
        for (int i = 0; i < 4; ++i) {
            af[i]  = *reinterpret_cast<const bf16x8*>(
                         &As[(wr * 64 + i * 16 + (lane & 15)) * 32 + (lane >> 4) * 8]);
            bfr[i] = *reinterpret_cast<const bf16x8*>(
                         &Bs[(wc * 64 + i * 16 + (lane & 15)) * 32 + (lane >> 4) * 8]);
        }
#pragma unroll
        for (int i = 0; i < 4; ++i)
#pragma unroll
            for (int j = 0; j < 4; ++j)
                acc[i][j] = __builtin_amdgcn_mfma_f32_16x16x32_bf16(
                                af[i], bfr[j], acc[i][j], 0, 0, 0);
    }

    const int rowb = blockIdx.y * 128 + wr * 64 + ((lane >> 4) << 2);
    const int colb = blockIdx.x * 128 + wc * 64 + (lane & 15);

    if (OMODE == 0) {
        bf16* C = (bf16*)Cv + zb * sC;
#pragma unroll
        for (int i = 0; i < 4; ++i)
#pragma unroll
            for (int j = 0; j < 4; ++j)
#pragma unroll
                for (int r = 0; r < 4; ++r)
                    C[(long)(rowb + i * 16 + r) * ldc + colb + j * 16] = (bf16)acc[i][j][r];
    } else {
        float* C = (float*)Cv + zb * sC;
#pragma unroll
        for (int i = 0; i < 4; ++i)
#pragma unroll
            for (int j = 0; j < 4; ++j)
#pragma unroll
                for (int r = 0; r < 4; ++r)
                    C[(long)(rowb + i * 16 + r) * ldc + colb + j * 16] = acc[i][j][r];
    }
}

// ---------------------------------- 2-block/CU 256^2 BK=32 logits GEMM -----
// A = att [8192][1024], Bt = Wlm_t [32000][1024], C = logits f32 + bias,
// fused per-(row,256-colblock) logsumexp partials.
// 512 thr = 8 waves (2M x 4N), per-wave 128x64.  BK=32 -> 64 KB static LDS
// -> 2 blocks/CU (16 waves): cross-block overlap hides stage latency and
// barrier drain (m114 mechanism) instead of intra-block pipelining.
// LDS layout [2 buf][256 rows][32 k], swizzle: slot s of row r holds k-group
// (s ^ (r&3)); frag read ko = 8*(hi ^ (l15&3)) -> 2-way bank alias = free.
__device__ __forceinline__ void stage32(const bf16* __restrict__ gbase, int kt,
                                        bf16* lbase, int tid)
{
#pragma unroll
    for (int p = 0; p < 2; ++p) {
        int lin  = p * 512 + tid;         // 0..1023
        int row  = lin >> 2;
        int slot = lin & 3;
        int ke   = ((slot ^ (row & 3)) << 3) + kt;
        gll16(gbase + (long)row * EMB + ke, lbase + lin * 8);
    }
}

__global__ __launch_bounds__(512, 4)
void gemm256_logits(const bf16* __restrict__ A, const bf16* __restrict__ Bt,
                    float* __restrict__ C, const float* __restrict__ bias,
                    float2* __restrict__ part)
{
    __shared__ bf16 As[2][8192];          // [buf][256*32]
    __shared__ bf16 Bs[2][8192];

    const int tid  = threadIdx.x;
    const int lane = tid & 63, wid = tid >> 6;
    const int wr = wid >> 2, wc = wid & 3;
    const int l15 = lane & 15, hi = lane >> 4;

    // bijective XCD swizzle: each XCD keeps its 4 A-panels (2MB) L2-hot and
    // sweeps all 125 B-panels.
    const int wg = blockIdx.x;
    const int xcd = wg & 7, c = wg >> 3;
    const int nb = c >> 2;                // [0,125)
    const int mb = xcd * 4 + (c & 3);     // [0,32)

    const bf16* Ab = A  + (long)(mb * 256) * EMB;
    const bf16* Bb = Bt + (long)(nb * 256) * EMB;

    f32x4 acc[8][4] = {};

    const int ko = 8 * (hi ^ (l15 & 3));  // swizzled k-offset (elements)
    const bf16* ApBase = &As[0][0] + (wr * 128 + l15) * 32 + ko;
    const bf16* BpBase = &Bs[0][0] + (wc * 64  + l15) * 32 + ko;

    stage32(Ab, 0, &As[0][0], tid);
    stage32(Bb, 0, &Bs[0][0], tid);
    __syncthreads();

#pragma unroll 1
    for (int t = 0; t < 32; ++t) {
        const int b = t & 1;
        if (t < 31) {
            stage32(Ab, (t + 1) * 32, &As[b ^ 1][0], tid);
            stage32(Bb, (t + 1) * 32, &Bs[b ^ 1][0], tid);
        }
        bf16x8 bfr[4];
#pragma unroll
        for (int n = 0; n < 4; ++n)
            bfr[n] = *(const bf16x8*)(BpBase + b * 8192 + n * 512);
#pragma unroll
        for (int m = 0; m < 8; ++m) {
            bf16x8 af = *(const bf16x8*)(ApBase + b * 8192 + m * 512);
#pragma unroll
            for (int n = 0; n < 4; ++n)
                acc[m][n] = __builtin_amdgcn_mfma_f32_16x16x32_bf16(
                                af, bfr[n], acc[m][n], 0, 0, 0);
        }
        __syncthreads();   // drains stage of t+1 (vmcnt) + frag reads done
    }

    // ---- epilogue: bias + store f32 + fused row-partial logsumexp ----
    float* pm = (float*)&As[0][0];            // [4][256]
    float* ps = pm + 1024;                    // [4][256]

    const long colbase = (long)nb * 256 + wc * 64 + l15;
    float bv[4];
#pragma unroll
    for (int n = 0; n < 4; ++n) bv[n] = bias[colbase + n * 16];

    const long rowbase = (long)mb * 256 + wr * 128;
#pragma unroll
    for (int m = 0; m < 8; ++m) {
#pragma unroll
        for (int r = 0; r < 4; ++r) {
            float v0 = acc[m][0][r] + bv[0];
            float v1 = acc[m][1][r] + bv[1];
            float v2 = acc[m][2][r] + bv[2];
            float v3 = acc[m][3][r] + bv[3];
            long row = rowbase + m * 16 + (hi << 2) + r;
            float* Cp = C + row * (long)VOCAB + colbase;
            Cp[0] = v0; Cp[16] = v1; Cp[32] = v2; Cp[48] = v3;

            float lm = fmaxf(fmaxf(v0, v1), fmaxf(v2, v3));
#pragma unroll
            for (int o = 1; o < 16; o <<= 1) lm = fmaxf(lm, __shfl_xor(lm, o));
            float sp = __expf(v0 - lm) + __expf(v1 - lm) +
                       __expf(v2 - lm) + __expf(v3 - lm);
#pragma unroll
            for (int o = 1; o < 16; o <<= 1) sp += __shfl_xor(sp, o);
            if (l15 == 0) {
                int rb = wr * 128 + m * 16 + (hi << 2) + r;
                pm[wc * 256 + rb] = lm;
                ps[wc * 256 + rb] = sp;
            }
        }
    }
    __syncthreads();
    if (tid < 256) {
        float m0 = pm[tid], m1 = pm[256 + tid], m2 = pm[512 + tid], m3 = pm[768 + tid];
        float M = fmaxf(fmaxf(m0, m1), fmaxf(m2, m3));
        float S = ps[tid] * __expf(m0 - M) + ps[256 + tid] * __expf(m1 - M) +
                  ps[512 + tid] * __expf(m2 - M) + ps[768 + tid] * __expf(m3 - M);
        part[((long)mb * 256 + tid) * 125 + nb] = make_float2(M, S);
    }
}

// ------------------------------------------------------ causal softmax -----
__global__ void softmax_causal_kernel(const bf16* __restrict__ S,
                                      bf16* __restrict__ P)
{
    const int r = blockIdx.x;
    const int t = r & (TLEN - 1);
    const int tid = threadIdx.x;
    const int lane = tid & 63, wv = tid >> 6;
    const float scale = 0.03125f;
    const int c0 = tid * 8;
    bf16x8 sv = *(const bf16x8*)(S + (long)r * TLEN + c0);

    float v[8];
    float m = -1e30f;
#pragma unroll
    for (int i = 0; i < 8; ++i) {
        float x = (c0 + i <= t) ? (float)sv[i] * scale : -1e30f;
        v[i] = x;
        m = fmaxf(m, x);
    }
    __shared__ float red[4];
#pragma unroll
    for (int off = 32; off; off >>= 1) m = fmaxf(m, __shfl_xor(m, off));
    if (lane == 0) red[wv] = m;
    __syncthreads();
    m = fmaxf(fmaxf(red[0], red[1]), fmaxf(red[2], red[3]));
    __syncthreads();

    float s = 0.f;
#pragma unroll
    for (int i = 0; i < 8; ++i) { v[i] = __expf(v[i] - m); s += v[i]; }
#pragma unroll
    for (int off = 32; off; off >>= 1) s += __shfl_xor(s, off);
    if (lane == 0) red[wv] = s;
    __syncthreads();
    s = red[0] + red[1] + red[2] + red[3];
    float inv = 1.0f / s;
    bf16x8 o;
#pragma unroll
    for (int i = 0; i < 8; ++i) o[i] = (bf16)(v[i] * inv);
    *(bf16x8*)(P + (long)r * TLEN + c0) = o;
}

// ------------------------------------------------------------- loss --------
__global__ void loss_combine_kernel(const float2* __restrict__ part,
                                    const float* __restrict__ logits,
                                    const int* __restrict__ tgt,
                                    float* __restrict__ bsum)
{
    const int tid = threadIdx.x;
    const int row = blockIdx.x * 256 + tid;
    const int lane = tid & 63, wv = tid >> 6;
    const float2* p = part + (long)row * 125;
    float M = -1e30f, S = 0.f;
    for (int i = 0; i < 125; ++i) {
        float2 v = p[i];
        if (v.x <= M) S += v.y * __expf(v.x - M);
        else { S = S * __expf(M - v.x) + v.y; M = v.x; }
    }
    float lse = M + __logf(S);
    float l = lse - logits[(long)row * VOCAB + tgt[row]];
#pragma unroll
    for (int off = 32; off; off >>= 1) l += __shfl_xor(l, off);
    __shared__ float red[4];
    if (lane == 0) red[wv] = l;
    __syncthreads();
    if (tid == 0) bsum[blockIdx.x] = red[0] + red[1] + red[2] + red[3];
}

__global__ void loss_final_kernel(const float* __restrict__ bsum,
                                  float* __restrict__ out)
{
    const int lane = threadIdx.x;
    float s = (lane < 32) ? bsum[lane] : 0.f;
#pragma unroll
    for (int off = 32; off; off >>= 1) s += __shfl_xor(s, off);
    if (lane == 0) out[0] = s * (1.0f / MTOT);
}

// ------------------------------------------------------------- launch ------
extern "C" void kernel_launch(void* const* d_in, const int* in_sizes, int n_in,
                              void* d_out, int out_size, void* d_ws, size_t ws_size,
                              hipStream_t stream)
{
    const int*   idx = (const int*)  d_in[0];
    const int*   tgt = (const int*)  d_in[1];
    const float* tok = (const float*)d_in[2];
    const float* pos = (const float*)d_in[3];
    const float* Wk  = (const float*)d_in[4];
    const float* Wq  = (const float*)d_in[5];
    const float* Wv  = (const float*)d_in[6];
    const float* Wlm = (const float*)d_in[7];
    const float* blm = (const float*)d_in[8];
    float* out = (float*)d_out;

    char* ws = (char*)d_ws;
    if (ws_size < (size_t)140 * 1024 * 1024) return;

    bf16*   x     = (bf16*)(ws);
    bf16*   qk    = (bf16*)(ws + (16l << 20));
    bf16*   v_t   = (bf16*)(ws + (48l << 20));
    bf16*   S     = (bf16*)(ws + (64l << 20));
    bf16*   Wqk_t = (bf16*)(ws + (96l << 20));
    bf16*   Wv_t  = (bf16*)(ws + (100l << 20));
    bf16*   att   = (bf16*)(ws);                  // over x
    bf16*   P     = (bf16*)(ws + (16l << 20));    // over qk
    bf16*   Wlm_t = (bf16*)(ws + (48l << 20));    // over v_t+S+W*_t after PV
    float2* part  = (float2*)(ws + (112l << 20));
    float*  bsum  = (float*)(ws + (120l << 20));

    // 1) embedding
    embed_kernel<<<dim3(MTOT * EMB / 8 / 256), 256, 0, stream>>>(idx, tok, pos, x);

    // 2) weight transposes (Wq|Wk stacked into one [2048][1024] operand)
    transpose_conv_kernel<<<dim3(16, 16), 256, 0, stream>>>(Wq, Wqk_t, EMB, EMB);
    transpose_conv_kernel<<<dim3(16, 16), 256, 0, stream>>>(Wk, Wqk_t + 1024 * 1024, EMB, EMB);
    transpose_conv_kernel<<<dim3(16, 16), 256, 0, stream>>>(Wv, Wv_t, EMB, EMB);

    // 3) qk = x @ [Wq|Wk];  v_t = Wv_t @ x^T
    gemm_bt_kernel<0><<<dim3(2048 / 128, MTOT / 128, 1), 256, 0, stream>>>(
        x, EMB, 0, Wqk_t, EMB, 0, qk, 2048, 0, EMB, nullptr);
    gemm_bt_kernel<0><<<dim3(MTOT / 128, EMB / 128, 1), 256, 0, stream>>>(
        Wv_t, EMB, 0, x, EMB, 0, v_t, MTOT, 0, EMB, nullptr);

    // 4) S = q @ k^T (per batch, bf16 out, unscaled)
    gemm_bt_kernel<0><<<dim3(TLEN / 128, TLEN / 128, NB), 256, 0, stream>>>(
        qk, 2048, (long)TLEN * 2048, qk + 1024, 2048, (long)TLEN * 2048,
        S, TLEN, (long)TLEN * TLEN, EMB, nullptr);

    // 5) P = softmax(causal(S * C^-0.5))
    softmax_causal_kernel<<<dim3(MTOT), 256, 0, stream>>>(S, P);

    // 6) att = P @ v
    gemm_bt_kernel<0><<<dim3(EMB / 128, TLEN / 128, NB), 256, 0, stream>>>(
        P, TLEN, (long)TLEN * TLEN, v_t, MTOT, (long)TLEN,
        att, EMB, (long)TLEN * EMB, TLEN, nullptr);

    // 7) Wlm transpose (into region freed by v_t/S/W*_t)
    transpose_conv_kernel<<<dim3(VOCAB / 64, EMB / 64), 256, 0, stream>>>(
        Wlm, Wlm_t, EMB, VOCAB);

    // 8) logits = att @ Wlm + blm, fused loss partials (2-block/CU BK=32)
    gemm256_logits<<<dim3(4000), 512, 0, stream>>>(att, Wlm_t, out, blm, part);

    // 9) loss
    loss_combine_kernel<<<dim3(32), 256, 0, stream>>>(part, out, tgt, bsum);
    loss_final_kernel<<<dim3(1), 64, 0, stream>>>(bsum, out + (long)MTOT * VOCAB);
}

// Round 6
// 1197.901 us; speedup vs baseline: 2.6250x; 2.6250x over previous
//
#include <hip/hip_runtime.h>
#include <hip/hip_bf16.h>
#include <cstdint>

#define VOCAB 32000
#define EMB   1024
#define TLEN  2048
#define NB    4
#define MTOT  (NB*TLEN)   // 8192 tokens

typedef __bf16 bf16;
typedef __bf16 bf16x8 __attribute__((ext_vector_type(8)));
typedef float  f32x4  __attribute__((ext_vector_type(4)));

// ---------------------------------------------------------------- embed ----
__global__ void embed_kernel(const int* __restrict__ idx,
                             const float* __restrict__ tok,
                             const float* __restrict__ pos,
                             bf16* __restrict__ x)
{
    int gid = blockIdx.x * 256 + threadIdx.x;
    int r   = gid >> 7;
    int c0  = (gid & 127) << 3;
    int t   = r & (TLEN - 1);
    int tk  = idx[r];
    const float4* tp = reinterpret_cast<const float4*>(tok + (long)tk * EMB + c0);
    const float4* pp = reinterpret_cast<const float4*>(pos + (long)t  * EMB + c0);
    float4 a0 = tp[0], a1 = tp[1];
    float4 b0 = pp[0], b1 = pp[1];
    bf16x8 o;
    o[0] = (bf16)(a0.x + b0.x); o[1] = (bf16)(a0.y + b0.y);
    o[2] = (bf16)(a0.z + b0.z); o[3] = (bf16)(a0.w + b0.w);
    o[4] = (bf16)(a1.x + b1.x); o[5] = (bf16)(a1.y + b1.y);
    o[6] = (bf16)(a1.z + b1.z); o[7] = (bf16)(a1.w + b1.w);
    *reinterpret_cast<bf16x8*>(x + (long)r * EMB + c0) = o;
}

// ------------------------------------------------- transpose + f32->bf16 ---
__global__ void transpose_conv_kernel(const float* __restrict__ W,
                                      bf16* __restrict__ Wt,
                                      int Kdim, int Ndim)
{
    __shared__ bf16 tile[64][65];
    int n0 = blockIdx.x * 64;
    int k0 = blockIdx.y * 64;
    int tid = threadIdx.x;
    int c  = tid & 63, r0 = tid >> 6;
#pragma unroll
    for (int i = 0; i < 16; ++i) {
        int r = r0 + i * 4;
        tile[r][c] = (bf16)W[(long)(k0 + r) * Ndim + n0 + c];
    }
    __syncthreads();
    int kc = tid & 63, nr0 = tid >> 6;
#pragma unroll
    for (int i = 0; i < 16; ++i) {
        int nr = nr0 + i * 4;
        Wt[(long)(n0 + nr) * Kdim + k0 + kc] = tile[kc][nr];
    }
}

// ------------------------------------------------------------- gll --------
__device__ __forceinline__ void gll16(const void* g, void* l)
{
    __builtin_amdgcn_global_load_lds(
        (const __attribute__((address_space(1))) unsigned int*)g,
        (__attribute__((address_space(3))) unsigned int*)l, 16, 0, 0);
}

// ------------------------------------------------- m97-style 128^2 GEMM ----
// C[M x N] = A[M x K] * Bt[N x K]^T, bf16 in, OMODE: 0 bf16 out, 1 f32 out
template<int OMODE>
__global__ __launch_bounds__(256)
void gemm_bt_kernel(const bf16* __restrict__ A, int lda, long sA,
                    const bf16* __restrict__ Bt, int ldb, long sB,
                    void* __restrict__ Cv, int ldc, long sC,
                    int K, const float* __restrict__ bias)
{
    __shared__ bf16 As[128 * 32];
    __shared__ bf16 Bs[128 * 32];

    const int tid  = threadIdx.x;
    const int lane = tid & 63;
    const int wv   = tid >> 6;
    const int wr   = wv >> 1, wc = wv & 1;
    const long zb  = blockIdx.z;

    const bf16* Ab = A  + zb * sA + (long)(blockIdx.y * 128) * lda;
    const bf16* Bb = Bt + zb * sB + (long)(blockIdx.x * 128) * ldb;

    f32x4 acc[4][4] = {};

    const int l0 = tid, l1 = tid + 256;
    const int r0s = l0 >> 2, kg0 = (l0 & 3) * 8;
    const int r1s = l1 >> 2, kg1 = (l1 & 3) * 8;

    for (int kt = 0; kt < K; kt += 32) {
        if (kt) __syncthreads();
        gll16(Ab + (long)r0s * lda + kt + kg0, &As[l0 * 8]);
        gll16(Ab + (long)r1s * lda + kt + kg1, &As[l1 * 8]);
        gll16(Bb + (long)r0s * ldb + kt + kg0, &Bs[l0 * 8]);
        gll16(Bb + (long)r1s * ldb + kt + kg1, &Bs[l1 * 8]);
        __syncthreads();

        bf16x8 af[4], bfr[4];
#pragma unroll
        for (int i = 0; i < 4; ++i) {
            af[i]  = *reinterpret_cast<const bf16x8*>(
                         &As[(wr * 64 + i * 16 + (lane & 15)) * 32 + (lane >> 4) * 8]);
            bfr[i] = *reinterpret_cast<const bf16x8*>(
                         &Bs[(wc * 64 + i * 16 + (lane & 15)) * 32 + (lane >> 4) * 8]);
        }
#pragma unroll
        for (int i = 0; i < 4; ++i)
#pragma unroll
            for (int j = 0; j < 4; ++j)
                acc[i][j] = __builtin_amdgcn_mfma_f32_16x16x32_bf16(
                                af[i], bfr[j], acc[i][j], 0, 0, 0);
    }

    const int rowb = blockIdx.y * 128 + wr * 64 + ((lane >> 4) << 2);
    const int colb = blockIdx.x * 128 + wc * 64 + (lane & 15);

    if (OMODE == 0) {
        bf16* C = (bf16*)Cv + zb * sC;
#pragma unroll
        for (int i = 0; i < 4; ++i)
#pragma unroll
            for (int j = 0; j < 4; ++j)
#pragma unroll
                for (int r = 0; r < 4; ++r)
                    C[(long)(rowb + i * 16 + r) * ldc + colb + j * 16] = (bf16)acc[i][j][r];
    } else {
        float* C = (float*)Cv + zb * sC;
#pragma unroll
        for (int i = 0; i < 4; ++i)
#pragma unroll
            for (int j = 0; j < 4; ++j)
#pragma unroll
                for (int r = 0; r < 4; ++r)
                    C[(long)(rowb + i * 16 + r) * ldc + colb + j * 16] = acc[i][j][r];
    }
}

// ------------------------- m97-structure 128^2 logits GEMM, 4 blocks/CU ----
// A = att [8192][1024], Bt = Wlm_t [32000][1024], C = logits f32 + bias,
// fused per-(row,128-colblock) logsumexp partials -> part[8192][250].
// 256 thr = 4 waves (2x2), wave tile 64x64, BK=32, 16 KB LDS, ~80 VGPR ->
// 4 blocks/CU: cross-block wave overlap (m114) hides the 2-phase barrier
// drain. Bijective XCD swizzle: 16000 wgs = 8 XCD x (8 mb x 250 nb);
// each XCD's 8 A-panels (2 MB) stay L2-hot, Wlm_t (62.5 MB) is L3-resident.
__global__ __launch_bounds__(256)
void gemm128_logits(const bf16* __restrict__ A, const bf16* __restrict__ Bt,
                    float* __restrict__ C, const float* __restrict__ bias,
                    float2* __restrict__ part)
{
    __shared__ bf16 As[128 * 32];
    __shared__ bf16 Bs[128 * 32];

    const int tid  = threadIdx.x;
    const int lane = tid & 63;
    const int wv   = tid >> 6;
    const int wr   = wv >> 1, wc = wv & 1;
    const int l15  = lane & 15, hi = lane >> 4;

    const int wg  = blockIdx.x;
    const int xcd = wg & 7, c = wg >> 3;       // c in [0,2000)
    const int mb  = xcd * 8 + (c & 7);         // [0,64)
    const int nb  = c >> 3;                    // [0,250)

    const bf16* Ab = A  + (long)(mb * 128) * EMB;
    const bf16* Bb = Bt + (long)(nb * 128) * EMB;

    f32x4 acc[4][4] = {};

    const int l0 = tid, l1 = tid + 256;
    const int r0s = l0 >> 2, kg0 = (l0 & 3) * 8;
    const int r1s = l1 >> 2, kg1 = (l1 & 3) * 8;

    for (int kt = 0; kt < EMB; kt += 32) {
        if (kt) __syncthreads();
        gll16(Ab + (long)r0s * EMB + kt + kg0, &As[l0 * 8]);
        gll16(Ab + (long)r1s * EMB + kt + kg1, &As[l1 * 8]);
        gll16(Bb + (long)r0s * EMB + kt + kg0, &Bs[l0 * 8]);
        gll16(Bb + (long)r1s * EMB + kt + kg1, &Bs[l1 * 8]);
        __syncthreads();

        bf16x8 af[4], bfr[4];
#pragma unroll
        for (int i = 0; i < 4; ++i) {
            af[i]  = *reinterpret_cast<const bf16x8*>(
                         &As[(wr * 64 + i * 16 + l15) * 32 + hi * 8]);
            bfr[i] = *reinterpret_cast<const bf16x8*>(
                         &Bs[(wc * 64 + i * 16 + l15) * 32 + hi * 8]);
        }
#pragma unroll
        for (int i = 0; i < 4; ++i)
#pragma unroll
            for (int j = 0; j < 4; ++j)
                acc[i][j] = __builtin_amdgcn_mfma_f32_16x16x32_bf16(
                                af[i], bfr[j], acc[i][j], 0, 0, 0);
    }

    // ---- epilogue: bias + f32 store + per-(row, nb) lse partial ----
    __syncthreads();                       // LDS reuse for reduction
    float* pm = (float*)As;                // [2][128]
    float* ps = pm + 256;                  // [2][128]

    const long colbase = (long)nb * 128 + wc * 64 + l15;
    float bv[4];
#pragma unroll
    for (int j = 0; j < 4; ++j) bv[j] = bias[colbase + j * 16];

    const long rowbase = (long)mb * 128 + wr * 64 + (hi << 2);
#pragma unroll
    for (int i = 0; i < 4; ++i) {
#pragma unroll
        for (int r = 0; r < 4; ++r) {
            float v0 = acc[i][0][r] + bv[0];
            float v1 = acc[i][1][r] + bv[1];
            float v2 = acc[i][2][r] + bv[2];
            float v3 = acc[i][3][r] + bv[3];
            long row = rowbase + i * 16 + r;
            float* Cp = C + row * (long)VOCAB + colbase;
            Cp[0] = v0; Cp[16] = v1; Cp[32] = v2; Cp[48] = v3;

            float lm = fmaxf(fmaxf(v0, v1), fmaxf(v2, v3));
#pragma unroll
            for (int o = 1; o < 16; o <<= 1) lm = fmaxf(lm, __shfl_xor(lm, o));
            float sp = __expf(v0 - lm) + __expf(v1 - lm) +
                       __expf(v2 - lm) + __expf(v3 - lm);
#pragma unroll
            for (int o = 1; o < 16; o <<= 1) sp += __shfl_xor(sp, o);
            if (l15 == 0) {
                int rb = wr * 64 + i * 16 + (hi << 2) + r;
                pm[wc * 128 + rb] = lm;
                ps[wc * 128 + rb] = sp;
            }
        }
    }
    __syncthreads();
    if (tid < 128) {
        float m0 = pm[tid], m1 = pm[128 + tid];
        float s0 = ps[tid], s1 = ps[128 + tid];
        float M = fmaxf(m0, m1);
        float S = s0 * __expf(m0 - M) + s1 * __expf(m1 - M);
        part[((long)mb * 128 + tid) * 250 + nb] = make_float2(M, S);
    }
}

// ------------------------------------------------------ causal softmax -----
__global__ void softmax_causal_kernel(const bf16* __restrict__ S,
                                      bf16* __restrict__ P)
{
    const int r = blockIdx.x;
    const int t = r & (TLEN - 1);
    const int tid = threadIdx.x;
    const int lane = tid & 63, wv = tid >> 6;
    const float scale = 0.03125f;
    const int c0 = tid * 8;
    bf16x8 sv = *(const bf16x8*)(S + (long)r * TLEN + c0);

    float v[8];
    float m = -1e30f;
#pragma unroll
    for (int i = 0; i < 8; ++i) {
        float x = (c0 + i <= t) ? (float)sv[i] * scale : -1e30f;
        v[i] = x;
        m = fmaxf(m, x);
    }
    __shared__ float red[4];
#pragma unroll
    for (int off = 32; off; off >>= 1) m = fmaxf(m, __shfl_xor(m, off));
    if (lane == 0) red[wv] = m;
    __syncthreads();
    m = fmaxf(fmaxf(red[0], red[1]), fmaxf(red[2], red[3]));
    __syncthreads();

    float s = 0.f;
#pragma unroll
    for (int i = 0; i < 8; ++i) { v[i] = __expf(v[i] - m); s += v[i]; }
#pragma unroll
    for (int off = 32; off; off >>= 1) s += __shfl_xor(s, off);
    if (lane == 0) red[wv] = s;
    __syncthreads();
    s = red[0] + red[1] + red[2] + red[3];
    float inv = 1.0f / s;
    bf16x8 o;
#pragma unroll
    for (int i = 0; i < 8; ++i) o[i] = (bf16)(v[i] * inv);
    *(bf16x8*)(P + (long)r * TLEN + c0) = o;
}

// ------------------------------------------------------------- loss --------
__global__ void loss_combine_kernel(const float2* __restrict__ part,
                                    const float* __restrict__ logits,
                                    const int* __restrict__ tgt,
                                    float* __restrict__ bsum)
{
    const int tid = threadIdx.x;
    const int row = blockIdx.x * 256 + tid;
    const int lane = tid & 63, wv = tid >> 6;
    const float2* p = part + (long)row * 250;
    float M = -1e30f, S = 0.f;
    for (int i = 0; i < 250; ++i) {
        float2 v = p[i];
        if (v.x <= M) S += v.y * __expf(v.x - M);
        else { S = S * __expf(M - v.x) + v.y; M = v.x; }
    }
    float lse = M + __logf(S);
    float l = lse - logits[(long)row * VOCAB + tgt[row]];
#pragma unroll
    for (int off = 32; off; off >>= 1) l += __shfl_xor(l, off);
    __shared__ float red[4];
    if (lane == 0) red[wv] = l;
    __syncthreads();
    if (tid == 0) bsum[blockIdx.x] = red[0] + red[1] + red[2] + red[3];
}

__global__ void loss_final_kernel(const float* __restrict__ bsum,
                                  float* __restrict__ out)
{
    const int lane = threadIdx.x;
    float s = (lane < 32) ? bsum[lane] : 0.f;
#pragma unroll
    for (int off = 32; off; off >>= 1) s += __shfl_xor(s, off);
    if (lane == 0) out[0] = s * (1.0f / MTOT);
}

// ------------------------------------------------------------- launch ------
extern "C" void kernel_launch(void* const* d_in, const int* in_sizes, int n_in,
                              void* d_out, int out_size, void* d_ws, size_t ws_size,
                              hipStream_t stream)
{
    const int*   idx = (const int*)  d_in[0];
    const int*   tgt = (const int*)  d_in[1];
    const float* tok = (const float*)d_in[2];
    const float* pos = (const float*)d_in[3];
    const float* Wk  = (const float*)d_in[4];
    const float* Wq  = (const float*)d_in[5];
    const float* Wv  = (const float*)d_in[6];
    const float* Wlm = (const float*)d_in[7];
    const float* blm = (const float*)d_in[8];
    float* out = (float*)d_out;

    char* ws = (char*)d_ws;
    if (ws_size < (size_t)140 * 1024 * 1024) return;

    bf16*   x     = (bf16*)(ws);
    bf16*   qk    = (bf16*)(ws + (16l << 20));
    bf16*   v_t   = (bf16*)(ws + (48l << 20));
    bf16*   S     = (bf16*)(ws + (64l << 20));
    bf16*   Wqk_t = (bf16*)(ws + (96l << 20));
    bf16*   Wv_t  = (bf16*)(ws + (100l << 20));
    bf16*   att   = (bf16*)(ws);                  // over x
    bf16*   P     = (bf16*)(ws + (16l << 20));    // over qk
    bf16*   Wlm_t = (bf16*)(ws + (48l << 20));    // over v_t+S+W*_t after PV
    float2* part  = (float2*)(ws + (112l << 20)); // [8192][250] f2 = 16.4 MB
    float*  bsum  = (float*)(ws + (130l << 20));

    // 1) embedding
    embed_kernel<<<dim3(MTOT * EMB / 8 / 256), 256, 0, stream>>>(idx, tok, pos, x);

    // 2) weight transposes (Wq|Wk stacked into one [2048][1024] operand)
    transpose_conv_kernel<<<dim3(16, 16), 256, 0, stream>>>(Wq, Wqk_t, EMB, EMB);
    transpose_conv_kernel<<<dim3(16, 16), 256, 0, stream>>>(Wk, Wqk_t + 1024 * 1024, EMB, EMB);
    transpose_conv_kernel<<<dim3(16, 16), 256, 0, stream>>>(Wv, Wv_t, EMB, EMB);

    // 3) qk = x @ [Wq|Wk];  v_t = Wv_t @ x^T
    gemm_bt_kernel<0><<<dim3(2048 / 128, MTOT / 128, 1), 256, 0, stream>>>(
        x, EMB, 0, Wqk_t, EMB, 0, qk, 2048, 0, EMB, nullptr);
    gemm_bt_kernel<0><<<dim3(MTOT / 128, EMB / 128, 1), 256, 0, stream>>>(
        Wv_t, EMB, 0, x, EMB, 0, v_t, MTOT, 0, EMB, nullptr);

    // 4) S = q @ k^T (per batch, bf16 out, unscaled)
    gemm_bt_kernel<0><<<dim3(TLEN / 128, TLEN / 128, NB), 256, 0, stream>>>(
        qk, 2048, (long)TLEN * 2048, qk + 1024, 2048, (long)TLEN * 2048,
        S, TLEN, (long)TLEN * TLEN, EMB, nullptr);

    // 5) P = softmax(causal(S * C^-0.5))
    softmax_causal_kernel<<<dim3(MTOT), 256, 0, stream>>>(S, P);

    // 6) att = P @ v
    gemm_bt_kernel<0><<<dim3(EMB / 128, TLEN / 128, NB), 256, 0, stream>>>(
        P, TLEN, (long)TLEN * TLEN, v_t, MTOT, (long)TLEN,
        att, EMB, (long)TLEN * EMB, TLEN, nullptr);

    // 7) Wlm transpose (into region freed by v_t/S/W*_t)
    transpose_conv_kernel<<<dim3(VOCAB / 64, EMB / 64), 256, 0, stream>>>(
        Wlm, Wlm_t, EMB, VOCAB);

    // 8) logits = att @ Wlm + blm, fused loss partials (128^2, 4 blocks/CU)
    gemm128_logits<<<dim3(16000), 256, 0, stream>>>(att, Wlm_t, out, blm, part);

    // 9) loss
    loss_combine_kernel<<<dim3(32), 256, 0, stream>>>(part, out, tgt, bsum);
    loss_final_kernel<<<dim3(1), 64, 0, stream>>>(bsum, out + (long)MTOT * VOCAB);
}

// Round 7
// 964.335 us; speedup vs baseline: 3.2607x; 1.2422x over previous
//
#include <hip/hip_runtime.h>
#include <hip/hip_bf16.h>
#include <cstdint>

#define VOCAB 32000
#define EMB   1024
#define TLEN  2048
#define NB    4
#define MTOT  (NB*TLEN)   // 8192 tokens

typedef __bf16 bf16;
typedef __bf16 bf16x8 __attribute__((ext_vector_type(8)));
typedef float  f32x4  __attribute__((ext_vector_type(4)));

// ---------------------------------------------------------------- embed ----
__global__ void embed_kernel(const int* __restrict__ idx,
                             const float* __restrict__ tok,
                             const float* __restrict__ pos,
                             bf16* __restrict__ x)
{
    int gid = blockIdx.x * 256 + threadIdx.x;
    int r   = gid >> 7;
    int c0  = (gid & 127) << 3;
    int t   = r & (TLEN - 1);
    int tk  = idx[r];
    const float4* tp = reinterpret_cast<const float4*>(tok + (long)tk * EMB + c0);
    const float4* pp = reinterpret_cast<const float4*>(pos + (long)t  * EMB + c0);
    float4 a0 = tp[0], a1 = tp[1];
    float4 b0 = pp[0], b1 = pp[1];
    bf16x8 o;
    o[0] = (bf16)(a0.x + b0.x); o[1] = (bf16)(a0.y + b0.y);
    o[2] = (bf16)(a0.z + b0.z); o[3] = (bf16)(a0.w + b0.w);
    o[4] = (bf16)(a1.x + b1.x); o[5] = (bf16)(a1.y + b1.y);
    o[6] = (bf16)(a1.z + b1.z); o[7] = (bf16)(a1.w + b1.w);
    *reinterpret_cast<bf16x8*>(x + (long)r * EMB + c0) = o;
}

// ------------------------------------------------- transpose + f32->bf16 ---
__global__ void transpose_conv_kernel(const float* __restrict__ W,
                                      bf16* __restrict__ Wt,
                                      int Kdim, int Ndim)
{
    __shared__ bf16 tile[64][65];
    int n0 = blockIdx.x * 64;
    int k0 = blockIdx.y * 64;
    int tid = threadIdx.x;
    int c  = tid & 63, r0 = tid >> 6;
#pragma unroll
    for (int i = 0; i < 16; ++i) {
        int r = r0 + i * 4;
        tile[r][c] = (bf16)W[(long)(k0 + r) * Ndim + n0 + c];
    }
    __syncthreads();
    int kc = tid & 63, nr0 = tid >> 6;
#pragma unroll
    for (int i = 0; i < 16; ++i) {
        int nr = nr0 + i * 4;
        Wt[(long)(n0 + nr) * Kdim + k0 + kc] = tile[kc][nr];
    }
}

// ------------------------------------------------------------- gll --------
__device__ __forceinline__ void gll16(const void* g, void* l)
{
    __builtin_amdgcn_global_load_lds(
        (const __attribute__((address_space(1))) unsigned int*)g,
        (__attribute__((address_space(3))) unsigned int*)l, 16, 0, 0);
}

// ------------------------------------------------- m97-style 128^2 GEMM ----
// C[M x N] = A[M x K] * Bt[N x K]^T, bf16 in, OMODE: 0 bf16 out, 1 f32 out
// LDS XOR swizzle (slot s of row r holds k-group s^(r&3); read at
// hi^(l15&3)) turns the old 4-way frag-read bank conflict into a free
// 2-way alias.
template<int OMODE>
__global__ __launch_bounds__(256)
void gemm_bt_kernel(const bf16* __restrict__ A, int lda, long sA,
                    const bf16* __restrict__ Bt, int ldb, long sB,
                    void* __restrict__ Cv, int ldc, long sC,
                    int K, const float* __restrict__ bias)
{
    __shared__ bf16 As[128 * 32];
    __shared__ bf16 Bs[128 * 32];

    const int tid  = threadIdx.x;
    const int lane = tid & 63;
    const int wv   = tid >> 6;
    const int wr   = wv >> 1, wc = wv & 1;
    const int l15  = lane & 15, hi = lane >> 4;
    const long zb  = blockIdx.z;

    const bf16* Ab = A  + zb * sA + (long)(blockIdx.y * 128) * lda;
    const bf16* Bb = Bt + zb * sB + (long)(blockIdx.x * 128) * ldb;

    f32x4 acc[4][4] = {};

    const int l0 = tid, l1 = tid + 256;
    const int r0s = l0 >> 2, kg0 = (((l0 & 3) ^ (r0s & 3))) * 8;
    const int r1s = l1 >> 2, kg1 = (((l1 & 3) ^ (r1s & 3))) * 8;
    const int kofr = (/*swizzled read slot*/ 0);
    (void)kofr;

    for (int kt = 0; kt < K; kt += 32) {
        if (kt) __syncthreads();
        gll16(Ab + (long)r0s * lda + kt + kg0, &As[l0 * 8]);
        gll16(Ab + (long)r1s * lda + kt + kg1, &As[l1 * 8]);
        gll16(Bb + (long)r0s * ldb + kt + kg0, &Bs[l0 * 8]);
        gll16(Bb + (long)r1s * ldb + kt + kg1, &Bs[l1 * 8]);
        __syncthreads();

        const int kos = (hi ^ (l15 & 3)) * 8;
        bf16x8 af[4], bfr[4];
#pragma unroll
        for (int i = 0; i < 4; ++i) {
            af[i]  = *reinterpret_cast<const bf16x8*>(
                         &As[(wr * 64 + i * 16 + l15) * 32 + kos]);
            bfr[i] = *reinterpret_cast<const bf16x8*>(
                         &Bs[(wc * 64 + i * 16 + l15) * 32 + kos]);
        }
#pragma unroll
        for (int i = 0; i < 4; ++i)
#pragma unroll
            for (int j = 0; j < 4; ++j)
                acc[i][j] = __builtin_amdgcn_mfma_f32_16x16x32_bf16(
                                af[i], bfr[j], acc[i][j], 0, 0, 0);
    }

    const int rowb = blockIdx.y * 128 + wr * 64 + (hi << 2);
    const int colb = blockIdx.x * 128 + wc * 64 + l15;

    if (OMODE == 0) {
        bf16* C = (bf16*)Cv + zb * sC;
#pragma unroll
        for (int i = 0; i < 4; ++i)
#pragma unroll
            for (int j = 0; j < 4; ++j)
#pragma unroll
                for (int r = 0; r < 4; ++r)
                    C[(long)(rowb + i * 16 + r) * ldc + colb + j * 16] = (bf16)acc[i][j][r];
    } else {
        float* C = (float*)Cv + zb * sC;
#pragma unroll
        for (int i = 0; i < 4; ++i)
#pragma unroll
            for (int j = 0; j < 4; ++j)
#pragma unroll
                for (int r = 0; r < 4; ++r)
                    C[(long)(rowb + i * 16 + r) * ldc + colb + j * 16] = acc[i][j][r];
    }
}

// --------------------- 256^2 logits GEMM, B 3-buf ring (2-tile lead) -------
// A = att [8192][1024] (L2-hot per XCD), Bt = Wlm_t [32000][1024] (L3).
// 512 thr = 8 waves (2M x 4N), BK=64. LDS = A 2x32KB + B 3x32KB = 160 KiB.
// Body t: issue stage A(t+1), B(t+2); R2 compute block (swizzled, 0-conflict);
// counted vmcnt(4) + s_barrier (retires B(t+1),A(t+1); keeps B(t+2) in
// flight). Never vmcnt(0) mid-loop. Fused bias + f32 store + lse partials.
__device__ __forceinline__ void stage256(const bf16* __restrict__ gbase, int kt,
                                         bf16* lbase, int tid)
{
#pragma unroll
    for (int p = 0; p < 4; ++p) {
        int lin  = p * 512 + tid;
        int row  = lin >> 3;
        int slot = lin & 7;
        int ke   = ((slot ^ (row & 7)) << 3) + kt;
        gll16(gbase + (long)row * EMB + ke, lbase + lin * 8);
    }
}

__global__ __launch_bounds__(512)
void gemm256_logits(const bf16* __restrict__ A, const bf16* __restrict__ Bt,
                    float* __restrict__ C, const float* __restrict__ bias,
                    float2* __restrict__ part)
{
    extern __shared__ bf16 smem[];        // 163840 B
    bf16* As = smem;                      // [2][16384]
    bf16* Bs = smem + 32768;              // [3][16384]

    const int tid  = threadIdx.x;
    const int lane = tid & 63, wid = tid >> 6;
    const int wr = wid >> 2, wc = wid & 3;
    const int l15 = lane & 15, hi = lane >> 4, l7 = lane & 7;

    // bijective XCD swizzle: each XCD keeps its 4 A-panels (2MB) L2-hot and
    // sweeps all 125 B-panels (all XCDs on the same nb concurrently -> L3).
    const int wg = blockIdx.x;
    const int xcd = wg & 7, c = wg >> 3;
    const int nb = c >> 2;                // [0,125)
    const int mb = xcd * 4 + (c & 3);     // [0,32)

    const bf16* Ab = A  + (long)(mb * 256) * EMB;
    const bf16* Bb = Bt + (long)(nb * 256) * EMB;

    f32x4 acc[8][4] = {};

    const int ko0 = 8 * (hi ^ l7);              // ks=0 swizzled k-offset
    const int ko1 = 8 * ((4 | hi) ^ l7);        // ks=1
    const bf16* ApR = As + (wr * 128 + l15) * 64;
    const bf16* BpR = Bs + (wc * 64  + l15) * 64;

    // prologue: A0, B0, B1; wait for A0,B0 (keep B1 in flight)
    stage256(Ab, 0,  As, tid);
    stage256(Bb, 0,  Bs, tid);
    stage256(Bb, 64, Bs + 16384, tid);
    asm volatile("s_waitcnt vmcnt(4)" ::: "memory");
    __builtin_amdgcn_sched_barrier(0);
    __builtin_amdgcn_s_barrier();

    int aB = 0, bB = 0;
#pragma unroll 1
    for (int t = 0; t < 16; ++t) {
        // issue stages: A(t+1) first, then B(t+2) (oldest-first order matters)
        if (t + 1 < 16)
            stage256(Ab, (t + 1) * 64, As + (aB ^ 1) * 16384, tid);
        if (t + 2 < 16) {
            int b2 = bB + 2; if (b2 >= 3) b2 -= 3;
            stage256(Bb, (t + 2) * 64, Bs + b2 * 16384, tid);
        }

        const bf16* Ap = ApR + aB * 16384;
        const bf16* Bp = BpR + bB * 16384;
#pragma unroll
        for (int ks = 0; ks < 2; ++ks) {
            const int ko = ks ? ko1 : ko0;
            bf16x8 bfr[4];
#pragma unroll
            for (int n = 0; n < 4; ++n)
                bfr[n] = *(const bf16x8*)(Bp + n * 1024 + ko);
#pragma unroll
            for (int m = 0; m < 8; ++m) {
                bf16x8 af = *(const bf16x8*)(Ap + m * 1024 + ko);
#pragma unroll
                for (int n = 0; n < 4; ++n)
                    acc[m][n] = __builtin_amdgcn_mfma_f32_16x16x32_bf16(
                                    af, bfr[n], acc[m][n], 0, 0, 0);
            }
        }

        // counted checkpoint: retire A(t+1)+B(t+1), keep B(t+2) in flight
        if (t < 14)       { asm volatile("s_waitcnt vmcnt(4)" ::: "memory"); }
        else if (t == 14) { asm volatile("s_waitcnt vmcnt(0)" ::: "memory"); }
        __builtin_amdgcn_sched_barrier(0);
        __builtin_amdgcn_s_barrier();

        aB ^= 1;
        bB = (bB == 2) ? 0 : bB + 1;
    }

    // ---- epilogue: bias + store f32 + fused row-partial logsumexp ----
    float* pm = (float*)smem;                 // [4][256]
    float* ps = pm + 1024;                    // [4][256]

    const long colbase = (long)nb * 256 + wc * 64 + l15;
    float bv[4];
#pragma unroll
    for (int n = 0; n < 4; ++n) bv[n] = bias[colbase + n * 16];

    const long rowbase = (long)mb * 256 + wr * 128;
#pragma unroll
    for (int m = 0; m < 8; ++m) {
#pragma unroll
        for (int r = 0; r < 4; ++r) {
            float v0 = acc[m][0][r] + bv[0];
            float v1 = acc[m][1][r] + bv[1];
            float v2 = acc[m][2][r] + bv[2];
            float v3 = acc[m][3][r] + bv[3];
            long row = rowbase + m * 16 + (hi << 2) + r;
            float* Cp = C + row * (long)VOCAB + colbase;
            Cp[0] = v0; Cp[16] = v1; Cp[32] = v2; Cp[48] = v3;

            float lm = fmaxf(fmaxf(v0, v1), fmaxf(v2, v3));
#pragma unroll
            for (int o = 1; o < 16; o <<= 1) lm = fmaxf(lm, __shfl_xor(lm, o));
            float sp = __expf(v0 - lm) + __expf(v1 - lm) +
                       __expf(v2 - lm) + __expf(v3 - lm);
#pragma unroll
            for (int o = 1; o < 16; o <<= 1) sp += __shfl_xor(sp, o);
            if (l15 == 0) {
                int rb = wr * 128 + m * 16 + (hi << 2) + r;
                pm[wc * 256 + rb] = lm;
                ps[wc * 256 + rb] = sp;
            }
        }
    }
    __syncthreads();
    if (tid < 256) {
        float m0 = pm[tid], m1 = pm[256 + tid], m2 = pm[512 + tid], m3 = pm[768 + tid];
        float M = fmaxf(fmaxf(m0, m1), fmaxf(m2, m3));
        float S = ps[tid] * __expf(m0 - M) + ps[256 + tid] * __expf(m1 - M) +
                  ps[512 + tid] * __expf(m2 - M) + ps[768 + tid] * __expf(m3 - M);
        part[((long)mb * 256 + tid) * 125 + nb] = make_float2(M, S);
    }
}

// ------------------------------------------------------ causal softmax -----
__global__ void softmax_causal_kernel(const bf16* __restrict__ S,
                                      bf16* __restrict__ P)
{
    const int r = blockIdx.x;
    const int t = r & (TLEN - 1);
    const int tid = threadIdx.x;
    const int lane = tid & 63, wv = tid >> 6;
    const float scale = 0.03125f;
    const int c0 = tid * 8;
    bf16x8 sv = *(const bf16x8*)(S + (long)r * TLEN + c0);

    float v[8];
    float m = -1e30f;
#pragma unroll
    for (int i = 0; i < 8; ++i) {
        float x = (c0 + i <= t) ? (float)sv[i] * scale : -1e30f;
        v[i] = x;
        m = fmaxf(m, x);
    }
    __shared__ float red[4];
#pragma unroll
    for (int off = 32; off; off >>= 1) m = fmaxf(m, __shfl_xor(m, off));
    if (lane == 0) red[wv] = m;
    __syncthreads();
    m = fmaxf(fmaxf(red[0], red[1]), fmaxf(red[2], red[3]));
    __syncthreads();

    float s = 0.f;
#pragma unroll
    for (int i = 0; i < 8; ++i) { v[i] = __expf(v[i] - m); s += v[i]; }
#pragma unroll
    for (int off = 32; off; off >>= 1) s += __shfl_xor(s, off);
    if (lane == 0) red[wv] = s;
    __syncthreads();
    s = red[0] + red[1] + red[2] + red[3];
    float inv = 1.0f / s;
    bf16x8 o;
#pragma unroll
    for (int i = 0; i < 8; ++i) o[i] = (bf16)(v[i] * inv);
    *(bf16x8*)(P + (long)r * TLEN + c0) = o;
}

// ------------------------------------------------------------- loss --------
__global__ void loss_combine_kernel(const float2* __restrict__ part,
                                    const float* __restrict__ logits,
                                    const int* __restrict__ tgt,
                                    float* __restrict__ bsum)
{
    const int tid = threadIdx.x;
    const int row = blockIdx.x * 256 + tid;
    const int lane = tid & 63, wv = tid >> 6;
    const float2* p = part + (long)row * 125;
    float M = -1e30f, S = 0.f;
    for (int i = 0; i < 125; ++i) {
        float2 v = p[i];
        if (v.x <= M) S += v.y * __expf(v.x - M);
        else { S = S * __expf(M - v.x) + v.y; M = v.x; }
    }
    float lse = M + __logf(S);
    float l = lse - logits[(long)row * VOCAB + tgt[row]];
#pragma unroll
    for (int off = 32; off; off >>= 1) l += __shfl_xor(l, off);
    __shared__ float red[4];
    if (lane == 0) red[wv] = l;
    __syncthreads();
    if (tid == 0) bsum[blockIdx.x] = red[0] + red[1] + red[2] + red[3];
}

__global__ void loss_final_kernel(const float* __restrict__ bsum,
                                  float* __restrict__ out)
{
    const int lane = threadIdx.x;
    float s = (lane < 32) ? bsum[lane] : 0.f;
#pragma unroll
    for (int off = 32; off; off >>= 1) s += __shfl_xor(s, off);
    if (lane == 0) out[0] = s * (1.0f / MTOT);
}

// ------------------------------------------------------------- launch ------
extern "C" void kernel_launch(void* const* d_in, const int* in_sizes, int n_in,
                              void* d_out, int out_size, void* d_ws, size_t ws_size,
                              hipStream_t stream)
{
    const int*   idx = (const int*)  d_in[0];
    const int*   tgt = (const int*)  d_in[1];
    const float* tok = (const float*)d_in[2];
    const float* pos = (const float*)d_in[3];
    const float* Wk  = (const float*)d_in[4];
    const float* Wq  = (const float*)d_in[5];
    const float* Wv  = (const float*)d_in[6];
    const float* Wlm = (const float*)d_in[7];
    const float* blm = (const float*)d_in[8];
    float* out = (float*)d_out;

    char* ws = (char*)d_ws;
    if (ws_size < (size_t)140 * 1024 * 1024) return;

    bf16*   x     = (bf16*)(ws);
    bf16*   qk    = (bf16*)(ws + (16l << 20));
    bf16*   v_t   = (bf16*)(ws + (48l << 20));
    bf16*   S     = (bf16*)(ws + (64l << 20));
    bf16*   Wqk_t = (bf16*)(ws + (96l << 20));
    bf16*   Wv_t  = (bf16*)(ws + (100l << 20));
    bf16*   att   = (bf16*)(ws);                  // over x
    bf16*   P     = (bf16*)(ws + (16l << 20));    // over qk
    bf16*   Wlm_t = (bf16*)(ws + (48l << 20));    // over v_t+S+W*_t after PV
    float2* part  = (float2*)(ws + (112l << 20));
    float*  bsum  = (float*)(ws + (120l << 20));

    // 1) embedding
    embed_kernel<<<dim3(MTOT * EMB / 8 / 256), 256, 0, stream>>>(idx, tok, pos, x);

    // 2) weight transposes (Wq|Wk stacked into one [2048][1024] operand)
    transpose_conv_kernel<<<dim3(16, 16), 256, 0, stream>>>(Wq, Wqk_t, EMB, EMB);
    transpose_conv_kernel<<<dim3(16, 16), 256, 0, stream>>>(Wk, Wqk_t + 1024 * 1024, EMB, EMB);
    transpose_conv_kernel<<<dim3(16, 16), 256, 0, stream>>>(Wv, Wv_t, EMB, EMB);

    // 3) qk = x @ [Wq|Wk];  v_t = Wv_t @ x^T
    gemm_bt_kernel<0><<<dim3(2048 / 128, MTOT / 128, 1), 256, 0, stream>>>(
        x, EMB, 0, Wqk_t, EMB, 0, qk, 2048, 0, EMB, nullptr);
    gemm_bt_kernel<0><<<dim3(MTOT / 128, EMB / 128, 1), 256, 0, stream>>>(
        Wv_t, EMB, 0, x, EMB, 0, v_t, MTOT, 0, EMB, nullptr);

    // 4) S = q @ k^T (per batch, bf16 out, unscaled)
    gemm_bt_kernel<0><<<dim3(TLEN / 128, TLEN / 128, NB), 256, 0, stream>>>(
        qk, 2048, (long)TLEN * 2048, qk + 1024, 2048, (long)TLEN * 2048,
        S, TLEN, (long)TLEN * TLEN, EMB, nullptr);

    // 5) P = softmax(causal(S * C^-0.5))
    softmax_causal_kernel<<<dim3(MTOT), 256, 0, stream>>>(S, P);

    // 6) att = P @ v
    gemm_bt_kernel<0><<<dim3(EMB / 128, TLEN / 128, NB), 256, 0, stream>>>(
        P, TLEN, (long)TLEN * TLEN, v_t, MTOT, (long)TLEN,
        att, EMB, (long)TLEN * EMB, TLEN, nullptr);

    // 7) Wlm transpose (into region freed by v_t/S/W*_t)
    transpose_conv_kernel<<<dim3(VOCAB / 64, EMB / 64), 256, 0, stream>>>(
        Wlm, Wlm_t, EMB, VOCAB);

    // 8) logits = att @ Wlm + blm, fused loss partials (B 3-buf ring, 160 KiB)
    gemm256_logits<<<dim3(4000), 512, 163840, stream>>>(att, Wlm_t, out, blm, part);

    // 9) loss
    loss_combine_kernel<<<dim3(32), 256, 0, stream>>>(part, out, tgt, bsum);
    loss_final_kernel<<<dim3(1), 64, 0, stream>>>(bsum, out + (long)MTOT * VOCAB);
}